// Round 4
// baseline (551.389 us; speedup 1.0000x reference)
//
#include <hip/hip_runtime.h>
#include <hip/hip_cooperative_groups.h>
#include <hip/hip_bf16.h>

namespace cg = cooperative_groups;

typedef __bf16 bf16_t;
typedef bf16_t bf16x8 __attribute__((ext_vector_type(8)));
typedef float  f32x4  __attribute__((ext_vector_type(4)));

#define BM 128
#define BN 96
#define BK 32   // A/B row = 4 chunks of 8 bf16 (16B units)

enum { EPI_NONE = 0, EPI_THRESH = 1, EPI_BIAS = 2 };

// LDS tile: unit(row, c) holds global chunk (c ^ (row&3)) of that row.
// Staging picks the swizzled GLOBAL chunk per lane (stays in the row's 64B
// segment -> coalesced; LDS dest is the hw-required base+lane*16).
// Fragment read of global chunk q of row r is at unit r*4 + (q ^ (r&3)).
template <int EPI, typename CT>
__device__ __forceinline__
void gemm_tile(const bf16_t* __restrict__ A, const bf16_t* __restrict__ B,
               CT* __restrict__ C, const float* __restrict__ bias,
               int m0, int n0, bf16_t* As, bf16_t* Bs)
{
    const int lane = threadIdx.x & 63;
    const int wave = threadIdx.x >> 6;
    const int wm = wave >> 1;
    const int wn = wave & 1;

    const int srow = lane >> 2;                       // 0..15
    const int scol = (lane & 3) ^ (srow & 3);         // swizzled global chunk

    const int fm = lane & 15;
    const int q  = lane >> 4;
    const int fsw = q ^ (fm & 3);                     // swizzled chunk for frag reads

    f32x4 acc[4][3];
#pragma unroll
    for (int i = 0; i < 4; i++)
#pragma unroll
        for (int j = 0; j < 3; j++) acc[i][j] = {0.f, 0.f, 0.f, 0.f};

    for (int k0 = 0; k0 < 768; k0 += BK) {
        // A: 128 rows x 4 units = 512 units; 2 issues of 64 per wave
#pragma unroll
        for (int i = 0; i < 2; i++) {
            const int u   = wave * 128 + i * 64;      // 16B-unit base (wave-uniform)
            const int row = (u >> 2) + srow;          // row&3 == srow&3
            const bf16_t* g = A + (size_t)(m0 + row) * 768 + k0 + scol * 8;
            __builtin_amdgcn_global_load_lds(
                (const __attribute__((address_space(1))) void*)g,
                (__attribute__((address_space(3))) void*)(As + (size_t)u * 8),
                16, 0, 0);
        }
        // B: 96 rows x 4 units = 384 units; 6 issues: jj = wave, wave+4
#pragma unroll
        for (int i = 0; i < 2; i++) {
            const int jj = wave + i * 4;
            if (jj < 6) {
                const int u   = jj * 64;
                const int row = jj * 16 + srow;
                const bf16_t* g = B + (size_t)(n0 + row) * 768 + k0 + scol * 8;
                __builtin_amdgcn_global_load_lds(
                    (const __attribute__((address_space(1))) void*)g,
                    (__attribute__((address_space(3))) void*)(Bs + (size_t)u * 8),
                    16, 0, 0);
            }
        }
        __syncthreads();

        bf16x8 af[4], bfr[3];
#pragma unroll
        for (int i = 0; i < 4; i++) {
            const int r = wm * 64 + i * 16 + fm;      // r&3 == fm&3
            af[i] = *(const bf16x8*)(As + (size_t)(r * 4 + fsw) * 8);
        }
#pragma unroll
        for (int j = 0; j < 3; j++) {
            const int r = wn * 48 + j * 16 + fm;
            bfr[j] = *(const bf16x8*)(Bs + (size_t)(r * 4 + fsw) * 8);
        }
#pragma unroll
        for (int i = 0; i < 4; i++)
#pragma unroll
            for (int j = 0; j < 3; j++)
                acc[i][j] = __builtin_amdgcn_mfma_f32_16x16x32_bf16(
                    af[i], bfr[j], acc[i][j], 0, 0, 0);
        __syncthreads();
    }

    // epilogue: C/D layout col=lane&15, row=quad*4+reg
#pragma unroll
    for (int i = 0; i < 4; i++) {
#pragma unroll
        for (int j = 0; j < 3; j++) {
            const int col = n0 + wn * 48 + j * 16 + fm;
            float bv = 0.f;
            if (EPI == EPI_BIAS) bv = bias[col];
#pragma unroll
            for (int r = 0; r < 4; r++) {
                const int row = m0 + wm * 64 + i * 16 + q * 4 + r;
                float v = acc[i][j][r];
                if (EPI == EPI_THRESH) v = (fabsf(v) > 1e-3f) ? v : 0.f;
                if (EPI == EPI_BIAS) v += bv;
                C[(size_t)row * 768 + col] = (CT)v;
            }
        }
    }
}

__device__ __forceinline__
void cvt8(const float* __restrict__ src, bf16_t* __restrict__ dst, long i)
{
    const f32x4 a = ((const f32x4*)src)[2 * i];
    const f32x4 b = ((const f32x4*)src)[2 * i + 1];
    bf16x8 o;
    o[0] = (bf16_t)a[0]; o[1] = (bf16_t)a[1]; o[2] = (bf16_t)a[2]; o[3] = (bf16_t)a[3];
    o[4] = (bf16_t)b[0]; o[5] = (bf16_t)b[1]; o[6] = (bf16_t)b[2]; o[7] = (bf16_t)b[3];
    ((bf16x8*)dst)[i] = o;
}

// One cooperative kernel: prep -> Wc+x-cvt -> h-GEMM -> out-GEMM.
__global__ __launch_bounds__(256, 4)
void fused(const float* __restrict__ x, const float* __restrict__ w,
           const float* __restrict__ bias, const float* __restrict__ U,
           const float* __restrict__ VT,
           bf16_t* __restrict__ xb, bf16_t* __restrict__ h,
           bf16_t* __restrict__ Ub, bf16_t* __restrict__ VTb,
           bf16_t* __restrict__ Wt, bf16_t* __restrict__ Wc,
           float* __restrict__ out)
{
    cg::grid_group grid = cg::this_grid();
    __shared__ __align__(16) bf16_t As[BM * BK];   // 8 KB
    __shared__ __align__(16) bf16_t Bs[BN * BK];   // 6 KB
    __shared__ float tt[32][33];                   // 4.2 KB (phase A only)

    const int G = gridDim.x;
    const int gtid = blockIdx.x * 256 + threadIdx.x;
    const int gstr = G * 256;

    // ---- phase A: convert U, VT; transpose+convert W ----
    for (int i = gtid; i < 2 * 73728; i += gstr) {   // 589824/8 chunks each
        if (i < 73728) cvt8(U, Ub, i);
        else           cvt8(VT, VTb, i - 73728);
    }
    for (int t = blockIdx.x; t < 576; t += G) {
        const int bx = (t % 24) * 32, by = (t / 24) * 32;
        const int tx = threadIdx.x & 31, ty = threadIdx.x >> 5;
        __syncthreads();
#pragma unroll
        for (int i = 0; i < 32; i += 8)
            tt[ty + i][tx] = w[(size_t)(by + ty + i) * 768 + bx + tx];
        __syncthreads();
#pragma unroll
        for (int i = 0; i < 32; i += 8)
            Wt[(size_t)(bx + ty + i) * 768 + by + tx] = (bf16_t)tt[tx][ty + i];
    }
    grid.sync();

    // ---- phase B: Wc = VTb @ Wt^T (blocks 0..47) || x -> bf16 (the rest) ----
    if (blockIdx.x < 48) {
        const int t = blockIdx.x;                    // 6x8 tiles of 768x768
        gemm_tile<EPI_NONE, bf16_t>(VTb, Wt, Wc, nullptr,
                                    (t >> 3) * BM, (t & 7) * BN, As, Bs);
    } else {
        const long t2 = (long)(blockIdx.x - 48) * 256 + threadIdx.x;
        const long s2 = (long)(G - 48) * 256;
        for (long i = t2; i < 3145728; i += s2)      // 25165824/8 chunks
            cvt8(x, xb, i);
    }
    grid.sync();

    // ---- phase 1: h = thresh(xb @ Ub^T) ; 2048 tiles (exactly 2/block @G=1024)
    for (int t = blockIdx.x; t < 2048; t += G)
        gemm_tile<EPI_THRESH, bf16_t>(xb, Ub, h, nullptr,
                                      (t >> 3) * BM, (t & 7) * BN, As, Bs);
    grid.sync();

    // ---- phase 2: out = h @ Wc^T + bias (fp32 store) ----
    for (int t = blockIdx.x; t < 2048; t += G)
        gemm_tile<EPI_BIAS, float>(h, Wc, out, bias,
                                   (t >> 3) * BM, (t & 7) * BN, As, Bs);
}

extern "C" void kernel_launch(void* const* d_in, const int* in_sizes, int n_in,
                              void* d_out, int out_size, void* d_ws, size_t ws_size,
                              hipStream_t stream)
{
    const float* x    = (const float*)d_in[0];   // (8,4096,768) fp32
    const float* w    = (const float*)d_in[1];   // (768,768)
    const float* bias = (const float*)d_in[2];   // (768,)
    const float* U    = (const float*)d_in[3];   // (768,768)
    const float* VT   = (const float*)d_in[4];   // (768,768)
    float* out = (float*)d_out;

    const int D = 768;
    const int M = 8 * 4096;
    const size_t MD = (size_t)M * D;
    const size_t DD = (size_t)D * D;

    char* ws = (char*)d_ws;
    bf16_t* xb  = (bf16_t*)ws;
    bf16_t* h   = (bf16_t*)(ws + MD * 2);
    bf16_t* Ub  = (bf16_t*)(ws + MD * 4);
    bf16_t* VTb = (bf16_t*)(ws + MD * 4 + DD * 2);
    bf16_t* Wt  = (bf16_t*)(ws + MD * 4 + DD * 4);
    bf16_t* Wc  = (bf16_t*)(ws + MD * 4 + DD * 6);

    int nb = 0;
    hipOccupancyMaxActiveBlocksPerMultiprocessor(&nb, fused, 256, 0);
    if (nb < 1) nb = 1;
    int G = 256 * nb;            // 256 CUs * blocks/CU
    if (G > 1024) G = 1024;      // 2048 tiles = exactly 2/block at 1024

    void* args[] = {(void*)&x, (void*)&w, (void*)&bias, (void*)&U, (void*)&VT,
                    (void*)&xb, (void*)&h, (void*)&Ub, (void*)&VTb,
                    (void*)&Wt, (void*)&Wc, (void*)&out};
    hipLaunchCooperativeKernel(fused, dim3(G), dim3(256), args, 0, stream);
}